// Round 7
// baseline (165.009 us; speedup 1.0000x reference)
//
#include <hip/hip_runtime.h>
#include <hip/hip_bf16.h>
#include <math.h>

// Single-head causal attention with fused QKV projection.
// B=16, T=4096, D_MODEL=512, HEAD_DIM=64. fp32 in/out, bf16 MFMA internally.
//
// R7: unroll-2 KV pipeline per wave (two independent QK->softmax->PV register
// streams, prefetch depth ~2 chains) on top of R6's in-register-P design
// (swapped 32x32 QK^T, cvt_pk + permlane32_swap, max-free softmax, scale
// pre-folded into Q). Unpaired LPT dispatch: 2048 blocks, qt descending per
// XCD, 4-way KV split per block, sum-merge through LDS.

#define NB 16
#define NT 4096
#define DMODEL 512
#define HD 64
#define CEXP 0.18033688011112042f   // log2(e)/8

typedef unsigned short u16;
typedef unsigned int u32;
typedef __attribute__((ext_vector_type(2))) unsigned int u32x2;
typedef __attribute__((ext_vector_type(8))) short bf16x8;
typedef __attribute__((ext_vector_type(4))) float f32x4;
typedef __attribute__((ext_vector_type(16))) float f32x16;

__device__ __forceinline__ u16 f2bf(float x) {
  union { float f; unsigned u; } v; v.f = x;
  unsigned r = v.u + 0x7fffu + ((v.u >> 16) & 1u);  // RNE
  return (u16)(r >> 16);
}

__device__ __forceinline__ u32 cvtpk(float lo, float hi) {
  u32 r;
  asm("v_cvt_pk_bf16_f32 %0, %1, %2" : "=v"(r) : "v"(lo), "v"(hi));
  return r;
}

// v_permlane32_swap_b32: a'[i<32]=a[i], a'[i>=32]=b[i-32]; b'[i<32]=a[i+32].
__device__ __forceinline__ u32x2 lane_swap(u32 a, u32 b) {
  asm("v_permlane32_swap_b32 %0, %1" : "+v"(a), "+v"(b));
  u32x2 r; r[0] = a; r[1] = b; return r;
}

#define MFMA32(a, b, c) __builtin_amdgcn_mfma_f32_16x16x32_bf16(a, b, c, 0, 0, 0)
#define WMFMA(a, b, c)  __builtin_amdgcn_mfma_f32_32x32x16_bf16(a, b, c, 0, 0, 0)
#define LD8(p) (*(const bf16x8*)(p))

// ---------------------------------------------------------------------------
// Kernel 1: Wt[n][k] = W_{n/64}[k][n%64] as bf16, n in [0,192), k in [0,512).
// ---------------------------------------------------------------------------
__global__ void prep_wt(const float* __restrict__ Wq, const float* __restrict__ Wk,
                        const float* __restrict__ Wv, u16* __restrict__ Wt) {
  int k0 = blockIdx.x * 16;
  int t = threadIdx.x;
#pragma unroll
  for (int i = 0; i < 12; ++i) {
    int idx = t + i * 256;      // [0, 3072)
    int n = idx % 192;
    int kk = idx / 192;         // [0, 16)
    const float* W = (n < 64) ? Wq : (n < 128) ? Wk : Wv;
    float w = W[(size_t)(k0 + kk) * 64 + (n & 63)];
    Wt[(size_t)n * 512 + k0 + kk] = f2bf(w);
  }
}

// ---------------------------------------------------------------------------
// Kernel 2: q = (x@Wq)*CEXP, k = x@Wk (row-major bf16 [B*T][64]);
//           v blocked-transposed: vt[b][t/32][d][t%32] (bf16).
// 512 threads (8 waves, 2x4), BM=128, BN=192, BK=32.
// ---------------------------------------------------------------------------
__global__ __launch_bounds__(512) void proj_qkv(const float* __restrict__ x,
                                                const u16* __restrict__ Wt,
                                                u16* __restrict__ qo,
                                                u16* __restrict__ ko,
                                                u16* __restrict__ vt) {
  __shared__ u16 As[128][48];   // 32 k + 16 pad
  int t = threadIdx.x;
  int m0 = blockIdx.x * 128;
  int lane = t & 63, wid = t >> 6;
  int wr = wid >> 2, wc = wid & 3;
  int g = lane >> 4, li = lane & 15;
  f32x4 acc[4][3];
#pragma unroll
  for (int i = 0; i < 4; ++i)
#pragma unroll
    for (int j = 0; j < 3; ++j) acc[i][j] = (f32x4){0.f, 0.f, 0.f, 0.f};

  int row = t >> 2, quad = t & 3;
  for (int k0 = 0; k0 < 512; k0 += 32) {
    __syncthreads();
    const float* src = x + (size_t)(m0 + row) * DMODEL + k0 + quad * 8;
    float4 f0 = *(const float4*)src;
    float4 f1 = *(const float4*)(src + 4);
    union { u16 s[8]; bf16x8 v; } tmp;
    tmp.s[0] = f2bf(f0.x); tmp.s[1] = f2bf(f0.y);
    tmp.s[2] = f2bf(f0.z); tmp.s[3] = f2bf(f0.w);
    tmp.s[4] = f2bf(f1.x); tmp.s[5] = f2bf(f1.y);
    tmp.s[6] = f2bf(f1.z); tmp.s[7] = f2bf(f1.w);
    *(bf16x8*)&As[row][quad * 8] = tmp.v;
    __syncthreads();

    bf16x8 a[4], bb[3];
#pragma unroll
    for (int mf = 0; mf < 4; ++mf)
      a[mf] = *(const bf16x8*)&As[wr * 64 + mf * 16 + li][g * 8];
#pragma unroll
    for (int nf = 0; nf < 3; ++nf)
      bb[nf] = *(const bf16x8*)(Wt + (size_t)(wc * 48 + nf * 16 + li) * 512 + k0 + g * 8);
#pragma unroll
    for (int mf = 0; mf < 4; ++mf)
#pragma unroll
      for (int nf = 0; nf < 3; ++nf)
        acc[mf][nf] = MFMA32(a[mf], bb[nf], acc[mf][nf]);
  }

  // D layout: col = lane&15, row = 4*(lane>>4)+r
#pragma unroll
  for (int nf = 0; nf < 3; ++nf) {
    int n = wc * 48 + nf * 16 + li;
    if (n < 128) {
      u16* dst = (n < 64) ? qo : ko;
      float sc = (n < 64) ? CEXP : 1.0f;   // fold softmax scale into Q (f32)
      int col = n & 63;
#pragma unroll
      for (int mf = 0; mf < 4; ++mf)
#pragma unroll
        for (int r = 0; r < 4; ++r) {
          int m = m0 + wr * 64 + mf * 16 + 4 * g + r;
          dst[(size_t)m * HD + col] = f2bf(acc[mf][nf][r] * sc);
        }
    } else {
      int d = n - 128;
#pragma unroll
      for (int mf = 0; mf < 4; ++mf) {
        int mbase = m0 + wr * 64 + mf * 16 + 4 * g;   // 4-aligned, within one batch
        int bb2 = mbase >> 12, tt = mbase & 4095;
        ushort4 pk;
        pk.x = f2bf(acc[mf][nf][0]);
        pk.y = f2bf(acc[mf][nf][1]);
        pk.z = f2bf(acc[mf][nf][2]);
        pk.w = f2bf(acc[mf][nf][3]);
        // vt[b][t/32][d][t%32]
        *(ushort4*)(vt + (((size_t)bb2 * 128 + (tt >> 5)) * 64 + d) * 32 + (tt & 31)) = pk;
      }
    }
  }
}

// ---------------------------------------------------------------------------
// Kernel 3: causal attention, max-free softmax, in-register P, unroll-2.
// Grid 2048 x 256 thr (4 waves). Block -> (batch, qt) with qt DESCENDING per
// XCD (LPT backfill), 2 batches per XCD. Wave w: KV tiles j = w, w+4, ...;
// two tiles in flight per iteration with independent register streams.
// ---------------------------------------------------------------------------
__global__ __launch_bounds__(256, 3) void attn_fwd7(const u16* __restrict__ qg,
                                                    const u16* __restrict__ kg,
                                                    const u16* __restrict__ vtg,
                                                    float* __restrict__ out) {
  __shared__ float Mrg[4][64][33];   // per-wave partials: o[32], l (pad 33)
  int t = threadIdx.x;
  int lane = t & 63, w = t >> 6;
  int l31 = lane & 31, h = lane >> 5;

  // LPT + XCD swizzle: xcd = f&7 owns batches {2xcd, 2xcd+1}; qt descending.
  int f = blockIdx.x;
  int xcd = f & 7, i = f >> 3;        // i in [0,256)
  int qt = 127 - (i >> 1);
  int b = 2 * xcd + (i & 1);

  const int q0 = qt * 32;
  const int lim = qt;                 // last 32-key KV tile index

  const u16* qb = qg + (size_t)b * NT * HD;
  const u16* kb = kg + (size_t)b * NT * HD;
  const u16* vb = vtg + (size_t)b * NT * HD;   // blocked [128][64][32]
  float* ob = out + (size_t)b * NT * HD;

  // Q fragments (B-operand): lane holds Q[q0+l31][dt*16 + 8h + j]
  bf16x8 qf[4];
#pragma unroll
  for (int dt = 0; dt < 4; ++dt)
    qf[dt] = LD8(qb + (size_t)(q0 + l31) * HD + dt * 16 + 8 * h);

  f32x16 oacc0, oacc1;   // O^T[d = dh*32 + (r&3)+8*(r>>2)+4h][q = q0+l31]
#pragma unroll
  for (int r = 0; r < 16; ++r) { oacc0[r] = 0.f; oacc1[r] = 0.f; }
  float lsum = 0.f;

  auto LOADK = [&](bf16x8 (&kf)[4], int jj) {
    const u16* p = kb + (size_t)jj * 2048 + l31 * 64 + 8 * h;
    kf[0] = LD8(p); kf[1] = LD8(p + 16); kf[2] = LD8(p + 32); kf[3] = LD8(p + 48);
  };
  auto LOADV = [&](bf16x8 (&vf)[4], int jj) {
    const u16* p = vb + (size_t)jj * 2048 + l31 * 32 + 8 * h;
    vf[0] = LD8(p); vf[1] = LD8(p + 1024); vf[2] = LD8(p + 16); vf[3] = LD8(p + 1040);
  };
  auto QK = [&](const bf16x8 (&kf)[4]) -> f32x16 {
    f32x16 sv;
#pragma unroll
    for (int r = 0; r < 16; ++r) sv[r] = 0.f;
    sv = WMFMA(kf[0], qf[0], sv);
    sv = WMFMA(kf[1], qf[1], sv);
    sv = WMFMA(kf[2], qf[2], sv);
    sv = WMFMA(kf[3], qf[3], sv);
    return sv;
  };
  auto EXP_PV = [&](f32x16 sv, const bf16x8 (&vf)[4], int jj) {
    if (jj == lim) {   // causal mask on diagonal tile (q0 cancels)
#pragma unroll
      for (int r = 0; r < 16; ++r) {
        int key = (r & 3) + 8 * (r >> 2) + 4 * h;
        if (key > l31) sv[r] = -1e30f;
      }
    }
    float p[16];
#pragma unroll
    for (int r = 0; r < 16; ++r) p[r] = __builtin_amdgcn_exp2f(sv[r]);
    lsum += (((p[0] + p[1]) + (p[2] + p[3])) + ((p[4] + p[5]) + (p[6] + p[7]))) +
            (((p[8] + p[9]) + (p[10] + p[11])) + ((p[12] + p[13]) + (p[14] + p[15])));
    u32 A0 = cvtpk(p[0], p[1]),   A1 = cvtpk(p[2], p[3]);    // keys 4h+{0..3}
    u32 B0 = cvtpk(p[4], p[5]),   B1 = cvtpk(p[6], p[7]);    // keys 8+4h
    u32 C0 = cvtpk(p[8], p[9]),   C1 = cvtpk(p[10], p[11]);  // keys 16+4h
    u32 E0 = cvtpk(p[12], p[13]), E1 = cvtpk(p[14], p[15]);  // keys 24+4h
    u32x2 s0 = lane_swap(A0, B0), s1 = lane_swap(A1, B1);
    u32x2 s2 = lane_swap(C0, E0), s3 = lane_swap(C1, E1);
    union { u32 d[4]; bf16x8 v; } f0u, f1u;   // B-frag: k = 8h+j
    f0u.d[0] = s0[0]; f0u.d[1] = s1[0]; f0u.d[2] = s0[1]; f0u.d[3] = s1[1];
    f1u.d[0] = s2[0]; f1u.d[1] = s3[0]; f1u.d[2] = s2[1]; f1u.d[3] = s3[1];
    oacc0 = WMFMA(vf[0], f0u.v, oacc0);
    oacc1 = WMFMA(vf[1], f0u.v, oacc1);
    oacc0 = WMFMA(vf[2], f1u.v, oacc0);
    oacc1 = WMFMA(vf[3], f1u.v, oacc1);
  };

  // unroll-2 pipeline: tiles jA and jB = jA+4 in flight per iteration
  bf16x8 kfA[4], vfA[4], kfB[4], vfB[4];
  int jA = w, jB = w + 4;
  if (jA <= lim) { LOADK(kfA, jA); LOADV(vfA, jA); }
  if (jB <= lim) { LOADK(kfB, jB); LOADV(vfB, jB); }

  for (; jA <= lim; jA += 8, jB += 8) {
    f32x16 svA = QK(kfA);
    bool moreB = (jB <= lim);
    f32x16 svB;
    if (moreB) svB = QK(kfB);
    if (jA + 8 <= lim) LOADK(kfA, jA + 8);
    if (jB + 8 <= lim) LOADK(kfB, jB + 8);
    EXP_PV(svA, vfA, jA);
    if (jA + 8 <= lim) LOADV(vfA, jA + 8);
    if (moreB) {
      EXP_PV(svB, vfB, jB);
      if (jB + 8 <= lim) LOADV(vfB, jB + 8);
    }
  }

  // merge the 4 wave partials
  {
    float* mg = &Mrg[w][lane][0];
#pragma unroll
    for (int r = 0; r < 16; ++r) { mg[r] = oacc0[r]; mg[16 + r] = oacc1[r]; }
    mg[32] = lsum;
  }
  __syncthreads();
  {
    float ls = 0.f;
#pragma unroll
    for (int w2 = 0; w2 < 4; ++w2)
      ls += Mrg[w2][l31][32] + Mrg[w2][l31 + 32][32];
    float inv = 1.0f / ls;
#pragma unroll
    for (int half = 0; half < 2; ++half) {
      int dq = w * 2 + h + half * 8;   // [0,16)
      float v[4];
#pragma unroll
      for (int dd = 0; dd < 4; ++dd) {
        int d = dq * 4 + dd;
        int dh = d >> 5, rem = d & 31;
        int srch = (rem >> 2) & 1;
        int reg = (rem & 3) + ((rem >> 3) << 2);
        float a = 0.f;
#pragma unroll
        for (int w2 = 0; w2 < 4; ++w2)
          a += Mrg[w2][l31 + 32 * srch][dh * 16 + reg];
        v[dd] = a * inv;
      }
      float4 o4; o4.x = v[0]; o4.y = v[1]; o4.z = v[2]; o4.w = v[3];
      *(float4*)(ob + (size_t)(q0 + l31) * HD + dq * 4) = o4;
    }
  }
}

// ---------------------------------------------------------------------------
extern "C" void kernel_launch(void* const* d_in, const int* in_sizes, int n_in,
                              void* d_out, int out_size, void* d_ws, size_t ws_size,
                              hipStream_t stream) {
  const float* x  = (const float*)d_in[0];
  const float* Wq = (const float*)d_in[1];
  const float* Wk = (const float*)d_in[2];
  const float* Wv = (const float*)d_in[3];
  float* out = (float*)d_out;

  // ws layout: Wt bf16 [192][512] | q [B*T][64] | k [B*T][64] | vt blocked
  u16* Wt  = (u16*)d_ws;
  u16* qws = (u16*)((char*)d_ws + 192 * 512 * 2);
  u16* kws = qws + (size_t)NB * NT * HD;
  u16* vtw = kws + (size_t)NB * NT * HD;

  prep_wt<<<32, 256, 0, stream>>>(Wq, Wk, Wv, Wt);
  proj_qkv<<<(NB * NT) / 128, 512, 0, stream>>>(x, Wt, qws, kws, vtw);
  attn_fwd7<<<2048, 256, 0, stream>>>(qws, kws, vtw, out);
}

// Round 8
// 127.789 us; speedup vs baseline: 1.2913x; 1.2913x over previous
//
#include <hip/hip_runtime.h>
#include <hip/hip_bf16.h>
#include <math.h>

// Single-head causal attention with fused QKV projection.
// B=16, T=4096, D_MODEL=512, HEAD_DIM=64. fp32 in/out, bf16 MFMA internally.
//
// R8: flash decomposition with LDS-shared KV. Block = 128 q-rows (4 waves x
// 32); K/V tiles staged once per block into a double-buffered LDS region via
// global_load_lds (counted vmcnt, 2 barriers/tile); waves read conflict-free
// 1KB-contiguous fragments. proj emits K/V pre-tiled in fragment order so
// staging and LDS reads are both linear. In-register P (swapped 32x32 QK^T +
// cvt_pk + permlane32_swap), max-free softmax, scale pre-folded into Q.

#define NB 16
#define NT 4096
#define DMODEL 512
#define HD 64
#define CEXP 0.18033688011112042f   // log2(e)/8

typedef unsigned short u16;
typedef unsigned int u32;
typedef __attribute__((ext_vector_type(2))) unsigned int u32x2;
typedef __attribute__((ext_vector_type(8))) short bf16x8;
typedef __attribute__((ext_vector_type(4))) float f32x4;
typedef __attribute__((ext_vector_type(16))) float f32x16;

__device__ __forceinline__ u16 f2bf(float x) {
  union { float f; unsigned u; } v; v.f = x;
  unsigned r = v.u + 0x7fffu + ((v.u >> 16) & 1u);  // RNE
  return (u16)(r >> 16);
}

__device__ __forceinline__ u32 cvtpk(float lo, float hi) {
  u32 r;
  asm("v_cvt_pk_bf16_f32 %0, %1, %2" : "=v"(r) : "v"(lo), "v"(hi));
  return r;
}

// v_permlane32_swap_b32: a'[i<32]=a[i], a'[i>=32]=b[i-32]; b'[i<32]=a[i+32].
__device__ __forceinline__ u32x2 lane_swap(u32 a, u32 b) {
  asm("v_permlane32_swap_b32 %0, %1" : "+v"(a), "+v"(b));
  u32x2 r; r[0] = a; r[1] = b; return r;
}

__device__ __forceinline__ void gload16(const void* g, void* l) {
  __builtin_amdgcn_global_load_lds(
      (const __attribute__((address_space(1))) void*)g,
      (__attribute__((address_space(3))) void*)l, 16, 0, 0);
}

#define MFMA32(a, b, c) __builtin_amdgcn_mfma_f32_16x16x32_bf16(a, b, c, 0, 0, 0)
#define WMFMA(a, b, c)  __builtin_amdgcn_mfma_f32_32x32x16_bf16(a, b, c, 0, 0, 0)
#define LD8(p) (*(const bf16x8*)(p))

// ---------------------------------------------------------------------------
// Kernel 1: Wt[n][k] = W_{n/64}[k][n%64] as bf16, n in [0,192), k in [0,512).
// ---------------------------------------------------------------------------
__global__ void prep_wt(const float* __restrict__ Wq, const float* __restrict__ Wk,
                        const float* __restrict__ Wv, u16* __restrict__ Wt) {
  int k0 = blockIdx.x * 16;
  int t = threadIdx.x;
#pragma unroll
  for (int i = 0; i < 12; ++i) {
    int idx = t + i * 256;      // [0, 3072)
    int n = idx % 192;
    int kk = idx / 192;         // [0, 16)
    const float* W = (n < 64) ? Wq : (n < 128) ? Wk : Wv;
    float w = W[(size_t)(k0 + kk) * 64 + (n & 63)];
    Wt[(size_t)n * 512 + k0 + kk] = f2bf(w);
  }
}

// ---------------------------------------------------------------------------
// Kernel 2: q = (x@Wq)*CEXP row-major bf16 [B*T][64];
//   k tiled fragment-order: kt[b*128+tile][dt][h][l31][8] = K[key][d]
//     (tile = key>>5, l31 = key&31, d = dt*16+8h+jj)
//   v tiled fragment-order: vt[b*128+tile][dh][kt][h][l31][8] = V[key][d]
//     (d = dh*32+l31, key-in-tile = kt*16+8h+jj)
// 512 threads (8 waves, 2x4), BM=128, BN=192, BK=32.
// ---------------------------------------------------------------------------
__global__ __launch_bounds__(512) void proj_qkv(const float* __restrict__ x,
                                                const u16* __restrict__ Wt,
                                                u16* __restrict__ qo,
                                                u16* __restrict__ ko,
                                                u16* __restrict__ vo) {
  __shared__ u16 As[128][48];   // 32 k + 16 pad
  int t = threadIdx.x;
  int m0 = blockIdx.x * 128;
  int lane = t & 63, wid = t >> 6;
  int wr = wid >> 2, wc = wid & 3;
  int g = lane >> 4, li = lane & 15;
  f32x4 acc[4][3];
#pragma unroll
  for (int i = 0; i < 4; ++i)
#pragma unroll
    for (int j = 0; j < 3; ++j) acc[i][j] = (f32x4){0.f, 0.f, 0.f, 0.f};

  int row = t >> 2, quad = t & 3;
  for (int k0 = 0; k0 < 512; k0 += 32) {
    __syncthreads();
    const float* src = x + (size_t)(m0 + row) * DMODEL + k0 + quad * 8;
    float4 f0 = *(const float4*)src;
    float4 f1 = *(const float4*)(src + 4);
    union { u16 s[8]; bf16x8 v; } tmp;
    tmp.s[0] = f2bf(f0.x); tmp.s[1] = f2bf(f0.y);
    tmp.s[2] = f2bf(f0.z); tmp.s[3] = f2bf(f0.w);
    tmp.s[4] = f2bf(f1.x); tmp.s[5] = f2bf(f1.y);
    tmp.s[6] = f2bf(f1.z); tmp.s[7] = f2bf(f1.w);
    *(bf16x8*)&As[row][quad * 8] = tmp.v;
    __syncthreads();

    bf16x8 a[4], bb[3];
#pragma unroll
    for (int mf = 0; mf < 4; ++mf)
      a[mf] = *(const bf16x8*)&As[wr * 64 + mf * 16 + li][g * 8];
#pragma unroll
    for (int nf = 0; nf < 3; ++nf)
      bb[nf] = *(const bf16x8*)(Wt + (size_t)(wc * 48 + nf * 16 + li) * 512 + k0 + g * 8);
#pragma unroll
    for (int mf = 0; mf < 4; ++mf)
#pragma unroll
      for (int nf = 0; nf < 3; ++nf)
        acc[mf][nf] = MFMA32(a[mf], bb[nf], acc[mf][nf]);
  }

  // D layout: col = lane&15, row = 4*(lane>>4)+r
#pragma unroll
  for (int nf = 0; nf < 3; ++nf) {
    int n = wc * 48 + nf * 16 + li;
    if (n < 64) {            // Q: row-major, scale folded
      int col = n;
#pragma unroll
      for (int mf = 0; mf < 4; ++mf)
#pragma unroll
        for (int r = 0; r < 4; ++r) {
          int m = m0 + wr * 64 + mf * 16 + 4 * g + r;
          qo[(size_t)m * HD + col] = f2bf(acc[mf][nf][r] * CEXP);
        }
    } else if (n < 128) {    // K: tiled fragment order
      int col = n & 63;
      int dt = col >> 4, hh = (col >> 3) & 1, jj = col & 7;
      size_t fo = (size_t)(dt * 2 + hh) * 256 + jj;
#pragma unroll
      for (int mf = 0; mf < 4; ++mf)
#pragma unroll
        for (int r = 0; r < 4; ++r) {
          int m = m0 + wr * 64 + mf * 16 + 4 * g + r;
          ko[(size_t)(m >> 5) * 2048 + fo + (m & 31) * 8] = f2bf(acc[mf][nf][r]);
        }
    } else {                 // V: tiled fragment order, ushort4 stores
      int d = n - 128;
      int dh = d >> 5, l31d = d & 31;
#pragma unroll
      for (int mf = 0; mf < 4; ++mf) {
        int mbase = m0 + wr * 64 + mf * 16 + 4 * g;   // 4-aligned
        int kk2 = mbase & 31;
        int kt2 = kk2 >> 4, hh = (kk2 >> 3) & 1;
        size_t off = (size_t)(mbase >> 5) * 2048 +
                     (size_t)((dh * 2 + kt2) * 2 + hh) * 256 + l31d * 8 + (mbase & 7);
        ushort4 pk;
        pk.x = f2bf(acc[mf][nf][0]);
        pk.y = f2bf(acc[mf][nf][1]);
        pk.z = f2bf(acc[mf][nf][2]);
        pk.w = f2bf(acc[mf][nf][3]);
        *(ushort4*)(vo + off) = pk;
      }
    }
  }
}

// ---------------------------------------------------------------------------
// Kernel 3: causal flash attention, LDS-shared KV, in-register P.
// Grid 512 x 256 thr (4 waves). Block -> (batch, 128-row q-block bp) via XCD
// swizzle + LPT (bp descending). Wave w owns rows [bp*128+w*32, +32).
// Per KV tile j: stage j+1 (global_load_lds x2/thread) -> vmcnt(2) -> barrier
// -> compute from buf[cur] -> barrier.
// ---------------------------------------------------------------------------
__global__ __launch_bounds__(256, 2) void attn_fwd8(const u16* __restrict__ qg,
                                                    const u16* __restrict__ kg,
                                                    const u16* __restrict__ vg,
                                                    float* __restrict__ out) {
  __shared__ u16 KV[2][4096];        // per buf: K tile 2048 | V tile 2048
  __shared__ float Mrg[4][64][33];   // per-wave O^T bounce for coalesced store
  int tid = threadIdx.x;
  int lane = tid & 63, w = tid >> 6;
  int l31 = lane & 31, h = lane >> 5;

  // XCD swizzle + LPT: xcd owns batches {2xcd, 2xcd+1}; bp descending.
  int f = blockIdx.x;
  int xcd = f & 7, i = f >> 3;        // i in [0,64)
  int b = 2 * xcd + (i & 1);
  int bp = 31 - (i >> 1);             // q-block [bp*128, bp*128+128)

  const int limb = 4 * bp + 3;        // last KV tile for the block
  const int limw = 4 * bp + w;        // last (and diagonal) KV tile for wave w
  const int q0w = bp * 128 + w * 32;

  const u16* qb = qg + (size_t)b * NT * HD;
  const u16* kbs = kg + (size_t)b * NT * HD;   // tiled [128][2048]
  const u16* vbs = vg + (size_t)b * NT * HD;
  float* ob = out + (size_t)b * NT * HD;

  // Q fragments (B-operand): lane holds Q[q0w+l31][dt*16 + 8h + jj]
  bf16x8 qf[4];
#pragma unroll
  for (int dt = 0; dt < 4; ++dt)
    qf[dt] = LD8(qb + (size_t)(q0w + l31) * HD + dt * 16 + 8 * h);

  f32x16 oacc0, oacc1;   // O^T[d = dh*32 + (r&3)+8*(r>>2)+4h][q = q0w+l31]
#pragma unroll
  for (int r = 0; r < 16; ++r) { oacc0[r] = 0.f; oacc1[r] = 0.f; }
  float lsum = 0.f;

  // prologue: stage tile 0 into buf 0
  gload16(kbs + tid * 8, &KV[0][tid * 8]);
  gload16(vbs + tid * 8, &KV[0][2048 + tid * 8]);

  int cur = 0;
  for (int j = 0; j <= limb; ++j) {
    if (j < limb) {   // stage next tile into the other buffer
      const u16* ks = kbs + (size_t)(j + 1) * 2048 + tid * 8;
      const u16* vs = vbs + (size_t)(j + 1) * 2048 + tid * 8;
      gload16(ks, &KV[cur ^ 1][tid * 8]);
      gload16(vs, &KV[cur ^ 1][2048 + tid * 8]);
      asm volatile("s_waitcnt vmcnt(2)" ::: "memory");   // tile j landed
    } else {
      asm volatile("s_waitcnt vmcnt(0)" ::: "memory");
    }
    __builtin_amdgcn_sched_barrier(0);
    asm volatile("s_barrier" ::: "memory");

    if (j <= limw) {
      const u16* kb0 = &KV[cur][0];
      const u16* vb0 = &KV[cur][2048];
      bf16x8 kf[4], vf[4];
#pragma unroll
      for (int dt = 0; dt < 4; ++dt)
        kf[dt] = LD8(kb0 + dt * 512 + h * 256 + l31 * 8);
#pragma unroll
      for (int dv = 0; dv < 4; ++dv)   // dv = dh*2+kt
        vf[dv] = LD8(vb0 + dv * 512 + h * 256 + l31 * 8);

      // S^T = K Q^T : row key = (r&3)+8*(r>>2)+4h, col q = l31
      f32x16 sv;
#pragma unroll
      for (int r = 0; r < 16; ++r) sv[r] = 0.f;
      sv = WMFMA(kf[0], qf[0], sv);
      sv = WMFMA(kf[1], qf[1], sv);
      sv = WMFMA(kf[2], qf[2], sv);
      sv = WMFMA(kf[3], qf[3], sv);

      if (j == limw) {   // diagonal tile: causal mask (q0 cancels)
#pragma unroll
        for (int r = 0; r < 16; ++r) {
          int key = (r & 3) + 8 * (r >> 2) + 4 * h;
          if (key > l31) sv[r] = -1e30f;
        }
      }

      float p[16];
#pragma unroll
      for (int r = 0; r < 16; ++r) p[r] = __builtin_amdgcn_exp2f(sv[r]);
      lsum += (((p[0] + p[1]) + (p[2] + p[3])) + ((p[4] + p[5]) + (p[6] + p[7]))) +
              (((p[8] + p[9]) + (p[10] + p[11])) + ((p[12] + p[13]) + (p[14] + p[15])));
      u32 A0 = cvtpk(p[0], p[1]),   A1 = cvtpk(p[2], p[3]);
      u32 B0 = cvtpk(p[4], p[5]),   B1 = cvtpk(p[6], p[7]);
      u32 C0 = cvtpk(p[8], p[9]),   C1 = cvtpk(p[10], p[11]);
      u32 E0 = cvtpk(p[12], p[13]), E1 = cvtpk(p[14], p[15]);
      u32x2 s0 = lane_swap(A0, B0), s1 = lane_swap(A1, B1);
      u32x2 s2 = lane_swap(C0, E0), s3 = lane_swap(C1, E1);
      union { u32 d[4]; bf16x8 v; } f0u, f1u;   // B-frag: k = 8h+jj
      f0u.d[0] = s0[0]; f0u.d[1] = s1[0]; f0u.d[2] = s0[1]; f0u.d[3] = s1[1];
      f1u.d[0] = s2[0]; f1u.d[1] = s3[0]; f1u.d[2] = s2[1]; f1u.d[3] = s3[1];

      oacc0 = WMFMA(vf[0], f0u.v, oacc0);   // dh=0, kt=0
      oacc1 = WMFMA(vf[2], f0u.v, oacc1);   // dh=1, kt=0
      oacc0 = WMFMA(vf[1], f1u.v, oacc0);   // dh=0, kt=1
      oacc1 = WMFMA(vf[3], f1u.v, oacc1);   // dh=1, kt=1
    }

    asm volatile("s_barrier" ::: "memory");
    cur ^= 1;
  }

  // normalize and store (per-wave, via LDS bounce for coalescing)
  lsum += __shfl_xor(lsum, 32);
  float inv = 1.0f / lsum;
#pragma unroll
  for (int r = 0; r < 16; ++r) { oacc0[r] *= inv; oacc1[r] *= inv; }

  {
    float* mg = &Mrg[w][lane][0];
#pragma unroll
    for (int r = 0; r < 16; ++r) { mg[r] = oacc0[r]; mg[16 + r] = oacc1[r]; }
  }
  __syncthreads();
#pragma unroll
  for (int s = 0; s < 8; ++s) {
    int ql = (lane >> 2) + 16 * (s & 1);    // [0,32)
    int dq = (lane & 3) + 4 * (s >> 1);     // [0,16)
    f32x4 o4;
#pragma unroll
    for (int dd = 0; dd < 4; ++dd) {
      int d = dq * 4 + dd;
      int dh = d >> 5, rem = d & 31;
      int srch = (rem >> 2) & 1;
      int reg = (rem & 3) + ((rem >> 3) << 2);
      o4[dd] = Mrg[w][ql + 32 * srch][dh * 16 + reg];
    }
    *(f32x4*)(ob + (size_t)(q0w + ql) * HD + dq * 4) = o4;
  }
}

// ---------------------------------------------------------------------------
extern "C" void kernel_launch(void* const* d_in, const int* in_sizes, int n_in,
                              void* d_out, int out_size, void* d_ws, size_t ws_size,
                              hipStream_t stream) {
  const float* x  = (const float*)d_in[0];
  const float* Wq = (const float*)d_in[1];
  const float* Wk = (const float*)d_in[2];
  const float* Wv = (const float*)d_in[3];
  float* out = (float*)d_out;

  // ws layout: Wt bf16 [192][512] | q [B*T][64] | k tiled | v tiled
  u16* Wt  = (u16*)d_ws;
  u16* qws = (u16*)((char*)d_ws + 192 * 512 * 2);
  u16* kws = qws + (size_t)NB * NT * HD;
  u16* vws = kws + (size_t)NB * NT * HD;

  prep_wt<<<32, 256, 0, stream>>>(Wq, Wk, Wv, Wt);
  proj_qkv<<<(NB * NT) / 128, 512, 0, stream>>>(x, Wt, qws, kws, vws);
  attn_fwd8<<<512, 256, 0, stream>>>(qws, kws, vws, out);
}

// Round 9
// 99.144 us; speedup vs baseline: 1.6643x; 1.2889x over previous
//
#include <hip/hip_runtime.h>
#include <hip/hip_bf16.h>
#include <math.h>

// Single-head causal attention with fused QKV projection.
// B=16, T=4096, D_MODEL=512, HEAD_DIM=64. fp32 in/out, bf16 MFMA internally.
//
// R9: flash with LDS-shared KV, 2 tiles per barrier round (counted vmcnt(4)),
// KV double-buffer unioned with the output-bounce LDS (33.8KB total), and a
// dispatch mapping that gives every CU exactly 132 tile-units (pairing 31-i
// with i across the two batches an XCD owns). In-register P path unchanged
// (swapped 32x32 QK^T, cvt_pk + permlane32_swap, max-free softmax).

#define NB 16
#define NT 4096
#define DMODEL 512
#define HD 64
#define CEXP 0.18033688011112042f   // log2(e)/8

typedef unsigned short u16;
typedef unsigned int u32;
typedef __attribute__((ext_vector_type(2))) unsigned int u32x2;
typedef __attribute__((ext_vector_type(8))) short bf16x8;
typedef __attribute__((ext_vector_type(4))) float f32x4;
typedef __attribute__((ext_vector_type(16))) float f32x16;

__device__ __forceinline__ u16 f2bf(float x) {
  union { float f; unsigned u; } v; v.f = x;
  unsigned r = v.u + 0x7fffu + ((v.u >> 16) & 1u);  // RNE
  return (u16)(r >> 16);
}

__device__ __forceinline__ u32 cvtpk(float lo, float hi) {
  u32 r;
  asm("v_cvt_pk_bf16_f32 %0, %1, %2" : "=v"(r) : "v"(lo), "v"(hi));
  return r;
}

// v_permlane32_swap_b32: a'[i<32]=a[i], a'[i>=32]=b[i-32]; b'[i<32]=a[i+32].
__device__ __forceinline__ u32x2 lane_swap(u32 a, u32 b) {
  asm("v_permlane32_swap_b32 %0, %1" : "+v"(a), "+v"(b));
  u32x2 r; r[0] = a; r[1] = b; return r;
}

__device__ __forceinline__ void gload16(const void* g, void* l) {
  __builtin_amdgcn_global_load_lds(
      (const __attribute__((address_space(1))) void*)g,
      (__attribute__((address_space(3))) void*)l, 16, 0, 0);
}

#define MFMA32(a, b, c) __builtin_amdgcn_mfma_f32_16x16x32_bf16(a, b, c, 0, 0, 0)
#define WMFMA(a, b, c)  __builtin_amdgcn_mfma_f32_32x32x16_bf16(a, b, c, 0, 0, 0)
#define LD8(p) (*(const bf16x8*)(p))

// ---------------------------------------------------------------------------
// Kernel 1: Wt[n][k] = W_{n/64}[k][n%64] as bf16, n in [0,192), k in [0,512).
// ---------------------------------------------------------------------------
__global__ void prep_wt(const float* __restrict__ Wq, const float* __restrict__ Wk,
                        const float* __restrict__ Wv, u16* __restrict__ Wt) {
  int k0 = blockIdx.x * 16;
  int t = threadIdx.x;
#pragma unroll
  for (int i = 0; i < 12; ++i) {
    int idx = t + i * 256;      // [0, 3072)
    int n = idx % 192;
    int kk = idx / 192;         // [0, 16)
    const float* W = (n < 64) ? Wq : (n < 128) ? Wk : Wv;
    float w = W[(size_t)(k0 + kk) * 64 + (n & 63)];
    Wt[(size_t)n * 512 + k0 + kk] = f2bf(w);
  }
}

// ---------------------------------------------------------------------------
// Kernel 2: q = (x@Wq)*CEXP row-major bf16 [B*T][64];
//   k tiled fragment-order: kt[b*128+tile][dt][h][l31][8] = K[key][d]
//   v tiled fragment-order: vt[b*128+tile][dh][kt][h][l31][8] = V[key][d]
// 512 threads (8 waves, 2x4), BM=128, BN=192, BK=32.
// ---------------------------------------------------------------------------
__global__ __launch_bounds__(512) void proj_qkv(const float* __restrict__ x,
                                                const u16* __restrict__ Wt,
                                                u16* __restrict__ qo,
                                                u16* __restrict__ ko,
                                                u16* __restrict__ vo) {
  __shared__ u16 As[128][48];   // 32 k + 16 pad
  int t = threadIdx.x;
  int m0 = blockIdx.x * 128;
  int lane = t & 63, wid = t >> 6;
  int wr = wid >> 2, wc = wid & 3;
  int g = lane >> 4, li = lane & 15;
  f32x4 acc[4][3];
#pragma unroll
  for (int i = 0; i < 4; ++i)
#pragma unroll
    for (int j = 0; j < 3; ++j) acc[i][j] = (f32x4){0.f, 0.f, 0.f, 0.f};

  int row = t >> 2, quad = t & 3;
  for (int k0 = 0; k0 < 512; k0 += 32) {
    __syncthreads();
    const float* src = x + (size_t)(m0 + row) * DMODEL + k0 + quad * 8;
    float4 f0 = *(const float4*)src;
    float4 f1 = *(const float4*)(src + 4);
    union { u16 s[8]; bf16x8 v; } tmp;
    tmp.s[0] = f2bf(f0.x); tmp.s[1] = f2bf(f0.y);
    tmp.s[2] = f2bf(f0.z); tmp.s[3] = f2bf(f0.w);
    tmp.s[4] = f2bf(f1.x); tmp.s[5] = f2bf(f1.y);
    tmp.s[6] = f2bf(f1.z); tmp.s[7] = f2bf(f1.w);
    *(bf16x8*)&As[row][quad * 8] = tmp.v;
    __syncthreads();

    bf16x8 a[4], bb[3];
#pragma unroll
    for (int mf = 0; mf < 4; ++mf)
      a[mf] = *(const bf16x8*)&As[wr * 64 + mf * 16 + li][g * 8];
#pragma unroll
    for (int nf = 0; nf < 3; ++nf)
      bb[nf] = *(const bf16x8*)(Wt + (size_t)(wc * 48 + nf * 16 + li) * 512 + k0 + g * 8);
#pragma unroll
    for (int mf = 0; mf < 4; ++mf)
#pragma unroll
      for (int nf = 0; nf < 3; ++nf)
        acc[mf][nf] = MFMA32(a[mf], bb[nf], acc[mf][nf]);
  }

  // D layout: col = lane&15, row = 4*(lane>>4)+r
#pragma unroll
  for (int nf = 0; nf < 3; ++nf) {
    int n = wc * 48 + nf * 16 + li;
    if (n < 64) {            // Q: row-major, scale folded
      int col = n;
#pragma unroll
      for (int mf = 0; mf < 4; ++mf)
#pragma unroll
        for (int r = 0; r < 4; ++r) {
          int m = m0 + wr * 64 + mf * 16 + 4 * g + r;
          qo[(size_t)m * HD + col] = f2bf(acc[mf][nf][r] * CEXP);
        }
    } else if (n < 128) {    // K: tiled fragment order
      int col = n & 63;
      int dt = col >> 4, hh = (col >> 3) & 1, jj = col & 7;
      size_t fo = (size_t)(dt * 2 + hh) * 256 + jj;
#pragma unroll
      for (int mf = 0; mf < 4; ++mf)
#pragma unroll
        for (int r = 0; r < 4; ++r) {
          int m = m0 + wr * 64 + mf * 16 + 4 * g + r;
          ko[(size_t)(m >> 5) * 2048 + fo + (m & 31) * 8] = f2bf(acc[mf][nf][r]);
        }
    } else {                 // V: tiled fragment order, ushort4 stores
      int d = n - 128;
      int dh = d >> 5, l31d = d & 31;
#pragma unroll
      for (int mf = 0; mf < 4; ++mf) {
        int mbase = m0 + wr * 64 + mf * 16 + 4 * g;   // 4-aligned
        int kk2 = mbase & 31;
        int kt2 = kk2 >> 4, hh = (kk2 >> 3) & 1;
        size_t off = (size_t)(mbase >> 5) * 2048 +
                     (size_t)((dh * 2 + kt2) * 2 + hh) * 256 + l31d * 8 + (mbase & 7);
        ushort4 pk;
        pk.x = f2bf(acc[mf][nf][0]);
        pk.y = f2bf(acc[mf][nf][1]);
        pk.z = f2bf(acc[mf][nf][2]);
        pk.w = f2bf(acc[mf][nf][3]);
        *(ushort4*)(vo + off) = pk;
      }
    }
  }
}

// ---------------------------------------------------------------------------
// Kernel 3: causal flash attention, LDS-shared KV, 2 tiles/barrier-round.
// Grid 512 x 256 thr (4 waves). Per XCD (f&7): i<32 -> (batch 2c, bp=31-i),
// i>=32 -> (batch 2c+1, bp=i-32)  => every CU's two blocks sum to 132 tiles.
// Round jr: stage tiles 2jr+2,2jr+3 -> vmcnt(4) -> barrier -> compute tiles
// 2jr, 2jr+1 -> barrier. KV dbuf (32KB) unioned with output bounce (33.8KB).
// ---------------------------------------------------------------------------
__global__ __launch_bounds__(256, 4) void attn_fwd9(const u16* __restrict__ qg,
                                                    const u16* __restrict__ kg,
                                                    const u16* __restrict__ vg,
                                                    float* __restrict__ out) {
  __shared__ __align__(16) char smem[33792];
  u16* KV = (u16*)smem;            // [2][8192]: K0|V0|K1|V1 per buf
  float* MrgF = (float*)smem;      // [4][64][33] after the loop

  int tid = threadIdx.x;
  int lane = tid & 63, w = tid >> 6;
  int l31 = lane & 31, h = lane >> 5;

  int f = blockIdx.x;
  int xcd = f & 7, i = f >> 3;     // i in [0,64)
  int b, bp;
  if (i < 32) { b = 2 * xcd;     bp = 31 - i; }
  else        { b = 2 * xcd + 1; bp = i - 32; }

  const int limw = 4 * bp + w;     // wave's last (diagonal) KV tile
  const int nr = 2 * bp + 2;       // rounds of 2 tiles
  const int q0w = bp * 128 + w * 32;

  const u16* qb = qg + (size_t)b * NT * HD;
  const u16* kbs = kg + (size_t)b * NT * HD;   // tiled [128][2048]
  const u16* vbs = vg + (size_t)b * NT * HD;
  float* ob = out + (size_t)b * NT * HD;

  // Q fragments (B-operand): lane holds Q[q0w+l31][dt*16 + 8h + jj]
  bf16x8 qf[4];
#pragma unroll
  for (int dt = 0; dt < 4; ++dt)
    qf[dt] = LD8(qb + (size_t)(q0w + l31) * HD + dt * 16 + 8 * h);

  f32x16 oacc0, oacc1;   // O^T[d = dh*32 + (r&3)+8*(r>>2)+4h][q = q0w+l31]
#pragma unroll
  for (int r = 0; r < 16; ++r) { oacc0[r] = 0.f; oacc1[r] = 0.f; }
  float lsum = 0.f;

  auto COMPUTE = [&](const u16* kp0, const u16* vp0, int j) {
    bf16x8 kf[4], vf[4];
#pragma unroll
    for (int dt = 0; dt < 4; ++dt)
      kf[dt] = LD8(kp0 + dt * 512 + h * 256 + l31 * 8);
#pragma unroll
    for (int dv = 0; dv < 4; ++dv)   // dv = dh*2+kt
      vf[dv] = LD8(vp0 + dv * 512 + h * 256 + l31 * 8);

    f32x16 sv;
#pragma unroll
    for (int r = 0; r < 16; ++r) sv[r] = 0.f;
    sv = WMFMA(kf[0], qf[0], sv);
    sv = WMFMA(kf[1], qf[1], sv);
    sv = WMFMA(kf[2], qf[2], sv);
    sv = WMFMA(kf[3], qf[3], sv);

    if (j == limw) {   // diagonal tile: causal mask (q0 cancels)
#pragma unroll
      for (int r = 0; r < 16; ++r) {
        int key = (r & 3) + 8 * (r >> 2) + 4 * h;
        if (key > l31) sv[r] = -1e30f;
      }
    }

    float p[16];
#pragma unroll
    for (int r = 0; r < 16; ++r) p[r] = __builtin_amdgcn_exp2f(sv[r]);
    lsum += (((p[0] + p[1]) + (p[2] + p[3])) + ((p[4] + p[5]) + (p[6] + p[7]))) +
            (((p[8] + p[9]) + (p[10] + p[11])) + ((p[12] + p[13]) + (p[14] + p[15])));
    u32 A0 = cvtpk(p[0], p[1]),   A1 = cvtpk(p[2], p[3]);
    u32 B0 = cvtpk(p[4], p[5]),   B1 = cvtpk(p[6], p[7]);
    u32 C0 = cvtpk(p[8], p[9]),   C1 = cvtpk(p[10], p[11]);
    u32 E0 = cvtpk(p[12], p[13]), E1 = cvtpk(p[14], p[15]);
    u32x2 s0 = lane_swap(A0, B0), s1 = lane_swap(A1, B1);
    u32x2 s2 = lane_swap(C0, E0), s3 = lane_swap(C1, E1);
    union { u32 d[4]; bf16x8 v; } f0u, f1u;   // B-frag: k = 8h+jj
    f0u.d[0] = s0[0]; f0u.d[1] = s1[0]; f0u.d[2] = s0[1]; f0u.d[3] = s1[1];
    f1u.d[0] = s2[0]; f1u.d[1] = s3[0]; f1u.d[2] = s2[1]; f1u.d[3] = s3[1];

    oacc0 = WMFMA(vf[0], f0u.v, oacc0);   // dh=0, kt=0
    oacc1 = WMFMA(vf[2], f0u.v, oacc1);   // dh=1, kt=0
    oacc0 = WMFMA(vf[1], f1u.v, oacc0);   // dh=0, kt=1
    oacc1 = WMFMA(vf[3], f1u.v, oacc1);   // dh=1, kt=1
  };

  // prologue: stage tiles 0,1 into buf 0
  gload16(kbs + tid * 8,        KV + tid * 8);
  gload16(vbs + tid * 8,        KV + 2048 + tid * 8);
  gload16(kbs + 2048 + tid * 8, KV + 4096 + tid * 8);
  gload16(vbs + 2048 + tid * 8, KV + 6144 + tid * 8);

  int cur = 0;
  for (int jr = 0; jr < nr; ++jr) {
    if (jr + 1 < nr) {   // stage next round's 2 tiles into the other buffer
      const u16* gk = kbs + (size_t)(2 * jr + 2) * 2048 + tid * 8;
      const u16* gv = vbs + (size_t)(2 * jr + 2) * 2048 + tid * 8;
      u16* lb = KV + (cur ^ 1) * 8192;
      gload16(gk,        lb + tid * 8);
      gload16(gv,        lb + 2048 + tid * 8);
      gload16(gk + 2048, lb + 4096 + tid * 8);
      gload16(gv + 2048, lb + 6144 + tid * 8);
      asm volatile("s_waitcnt vmcnt(4)" ::: "memory");   // this round landed
    } else {
      asm volatile("s_waitcnt vmcnt(0)" ::: "memory");
    }
    __builtin_amdgcn_sched_barrier(0);
    asm volatile("s_barrier" ::: "memory");

    const u16* kv0 = KV + cur * 8192;
    int jA = 2 * jr, jB = 2 * jr + 1;
    if (jA <= limw) COMPUTE(kv0, kv0 + 2048, jA);
    if (jB <= limw) COMPUTE(kv0 + 4096, kv0 + 6144, jB);

    asm volatile("s_barrier" ::: "memory");
    cur ^= 1;
  }

  // normalize and store (via LDS bounce for coalescing; KV no longer needed)
  lsum += __shfl_xor(lsum, 32);
  float inv = 1.0f / lsum;
#pragma unroll
  for (int r = 0; r < 16; ++r) { oacc0[r] *= inv; oacc1[r] *= inv; }

  {
    float* mg = MrgF + ((size_t)w * 64 + lane) * 33;
#pragma unroll
    for (int r = 0; r < 16; ++r) { mg[r] = oacc0[r]; mg[16 + r] = oacc1[r]; }
  }
  __syncthreads();
#pragma unroll
  for (int s = 0; s < 8; ++s) {
    int ql = (lane >> 2) + 16 * (s & 1);    // [0,32)
    int dq = (lane & 3) + 4 * (s >> 1);     // [0,16)
    f32x4 o4;
#pragma unroll
    for (int dd = 0; dd < 4; ++dd) {
      int d = dq * 4 + dd;
      int dh = d >> 5, rem = d & 31;
      int srch = (rem >> 2) & 1;
      int reg = (rem & 3) + ((rem >> 3) << 2);
      o4[dd] = MrgF[((size_t)w * 64 + ql + 32 * srch) * 33 + dh * 16 + reg];
    }
    *(f32x4*)(ob + (size_t)(q0w + ql) * HD + dq * 4) = o4;
  }
}

// ---------------------------------------------------------------------------
extern "C" void kernel_launch(void* const* d_in, const int* in_sizes, int n_in,
                              void* d_out, int out_size, void* d_ws, size_t ws_size,
                              hipStream_t stream) {
  const float* x  = (const float*)d_in[0];
  const float* Wq = (const float*)d_in[1];
  const float* Wk = (const float*)d_in[2];
  const float* Wv = (const float*)d_in[3];
  float* out = (float*)d_out;

  // ws layout: Wt bf16 [192][512] | q [B*T][64] | k tiled | v tiled
  u16* Wt  = (u16*)d_ws;
  u16* qws = (u16*)((char*)d_ws + 192 * 512 * 2);
  u16* kws = qws + (size_t)NB * NT * HD;
  u16* vws = kws + (size_t)NB * NT * HD;

  prep_wt<<<32, 256, 0, stream>>>(Wq, Wk, Wv, Wt);
  proj_qkv<<<(NB * NT) / 128, 512, 0, stream>>>(x, Wt, qws, kws, vws);
  attn_fwd9<<<512, 256, 0, stream>>>(qws, kws, vws, out);
}

// Round 10
// 96.751 us; speedup vs baseline: 1.7055x; 1.0247x over previous
//
#include <hip/hip_runtime.h>
#include <hip/hip_bf16.h>
#include <math.h>

// Single-head causal attention with fused QKV projection.
// B=16, T=4096, D_MODEL=512, HEAD_DIM=64. fp32 in/out, bf16 MFMA internally.
//
// R10: 64-row blocks x 4 waves = (q-tile qi) x (KV parity ki); 1024 blocks =
// 4 blocks/CU = 16 waves/CU (4/SIMD), 4 independent barrier domains per CU.
// KV staged once per block into double-buffered LDS (2 tiles/round, counted
// vmcnt(4), 2 barriers/round); per-CU workloads exactly equal (260 staged
// tiles, 516 wave-visits). In-register P core unchanged (swapped 32x32 QK^T,
// cvt_pk + permlane32_swap, max-free softmax, scale pre-folded into Q).

#define NB 16
#define NT 4096
#define DMODEL 512
#define HD 64
#define CEXP 0.18033688011112042f   // log2(e)/8

typedef unsigned short u16;
typedef unsigned int u32;
typedef __attribute__((ext_vector_type(2))) unsigned int u32x2;
typedef __attribute__((ext_vector_type(8))) short bf16x8;
typedef __attribute__((ext_vector_type(4))) float f32x4;
typedef __attribute__((ext_vector_type(16))) float f32x16;

__device__ __forceinline__ u16 f2bf(float x) {
  union { float f; unsigned u; } v; v.f = x;
  unsigned r = v.u + 0x7fffu + ((v.u >> 16) & 1u);  // RNE
  return (u16)(r >> 16);
}

__device__ __forceinline__ u32 cvtpk(float lo, float hi) {
  u32 r;
  asm("v_cvt_pk_bf16_f32 %0, %1, %2" : "=v"(r) : "v"(lo), "v"(hi));
  return r;
}

// v_permlane32_swap_b32: a'[i<32]=a[i], a'[i>=32]=b[i-32]; b'[i<32]=a[i+32].
__device__ __forceinline__ u32x2 lane_swap(u32 a, u32 b) {
  asm("v_permlane32_swap_b32 %0, %1" : "+v"(a), "+v"(b));
  u32x2 r; r[0] = a; r[1] = b; return r;
}

__device__ __forceinline__ void gload16(const void* g, void* l) {
  __builtin_amdgcn_global_load_lds(
      (const __attribute__((address_space(1))) void*)g,
      (__attribute__((address_space(3))) void*)l, 16, 0, 0);
}

#define MFMA32(a, b, c) __builtin_amdgcn_mfma_f32_16x16x32_bf16(a, b, c, 0, 0, 0)
#define WMFMA(a, b, c)  __builtin_amdgcn_mfma_f32_32x32x16_bf16(a, b, c, 0, 0, 0)
#define LD8(p) (*(const bf16x8*)(p))

// ---------------------------------------------------------------------------
// Kernel 1: Wt[n][k] = W_{n/64}[k][n%64] as bf16, n in [0,192), k in [0,512).
// ---------------------------------------------------------------------------
__global__ void prep_wt(const float* __restrict__ Wq, const float* __restrict__ Wk,
                        const float* __restrict__ Wv, u16* __restrict__ Wt) {
  int k0 = blockIdx.x * 16;
  int t = threadIdx.x;
#pragma unroll
  for (int i = 0; i < 12; ++i) {
    int idx = t + i * 256;      // [0, 3072)
    int n = idx % 192;
    int kk = idx / 192;         // [0, 16)
    const float* W = (n < 64) ? Wq : (n < 128) ? Wk : Wv;
    float w = W[(size_t)(k0 + kk) * 64 + (n & 63)];
    Wt[(size_t)n * 512 + k0 + kk] = f2bf(w);
  }
}

// ---------------------------------------------------------------------------
// Kernel 2: q = (x@Wq)*CEXP row-major bf16 [B*T][64];
//   k tiled fragment-order: kt[b*128+tile][dt][h][l31][8] = K[key][d]
//   v tiled fragment-order: vt[b*128+tile][dh][kt][h][l31][8] = V[key][d]
// 512 threads (8 waves, 2x4), BM=128, BN=192, BK=32.
// ---------------------------------------------------------------------------
__global__ __launch_bounds__(512) void proj_qkv(const float* __restrict__ x,
                                                const u16* __restrict__ Wt,
                                                u16* __restrict__ qo,
                                                u16* __restrict__ ko,
                                                u16* __restrict__ vo) {
  __shared__ u16 As[128][48];   // 32 k + 16 pad
  int t = threadIdx.x;
  int m0 = blockIdx.x * 128;
  int lane = t & 63, wid = t >> 6;
  int wr = wid >> 2, wc = wid & 3;
  int g = lane >> 4, li = lane & 15;
  f32x4 acc[4][3];
#pragma unroll
  for (int i = 0; i < 4; ++i)
#pragma unroll
    for (int j = 0; j < 3; ++j) acc[i][j] = (f32x4){0.f, 0.f, 0.f, 0.f};

  int row = t >> 2, quad = t & 3;
  for (int k0 = 0; k0 < 512; k0 += 32) {
    __syncthreads();
    const float* src = x + (size_t)(m0 + row) * DMODEL + k0 + quad * 8;
    float4 f0 = *(const float4*)src;
    float4 f1 = *(const float4*)(src + 4);
    union { u16 s[8]; bf16x8 v; } tmp;
    tmp.s[0] = f2bf(f0.x); tmp.s[1] = f2bf(f0.y);
    tmp.s[2] = f2bf(f0.z); tmp.s[3] = f2bf(f0.w);
    tmp.s[4] = f2bf(f1.x); tmp.s[5] = f2bf(f1.y);
    tmp.s[6] = f2bf(f1.z); tmp.s[7] = f2bf(f1.w);
    *(bf16x8*)&As[row][quad * 8] = tmp.v;
    __syncthreads();

    bf16x8 a[4], bb[3];
#pragma unroll
    for (int mf = 0; mf < 4; ++mf)
      a[mf] = *(const bf16x8*)&As[wr * 64 + mf * 16 + li][g * 8];
#pragma unroll
    for (int nf = 0; nf < 3; ++nf)
      bb[nf] = *(const bf16x8*)(Wt + (size_t)(wc * 48 + nf * 16 + li) * 512 + k0 + g * 8);
#pragma unroll
    for (int mf = 0; mf < 4; ++mf)
#pragma unroll
      for (int nf = 0; nf < 3; ++nf)
        acc[mf][nf] = MFMA32(a[mf], bb[nf], acc[mf][nf]);
  }

  // D layout: col = lane&15, row = 4*(lane>>4)+r
#pragma unroll
  for (int nf = 0; nf < 3; ++nf) {
    int n = wc * 48 + nf * 16 + li;
    if (n < 64) {            // Q: row-major, scale folded
      int col = n;
#pragma unroll
      for (int mf = 0; mf < 4; ++mf)
#pragma unroll
        for (int r = 0; r < 4; ++r) {
          int m = m0 + wr * 64 + mf * 16 + 4 * g + r;
          qo[(size_t)m * HD + col] = f2bf(acc[mf][nf][r] * CEXP);
        }
    } else if (n < 128) {    // K: tiled fragment order
      int col = n & 63;
      int dt = col >> 4, hh = (col >> 3) & 1, jj = col & 7;
      size_t fo = (size_t)(dt * 2 + hh) * 256 + jj;
#pragma unroll
      for (int mf = 0; mf < 4; ++mf)
#pragma unroll
        for (int r = 0; r < 4; ++r) {
          int m = m0 + wr * 64 + mf * 16 + 4 * g + r;
          ko[(size_t)(m >> 5) * 2048 + fo + (m & 31) * 8] = f2bf(acc[mf][nf][r]);
        }
    } else {                 // V: tiled fragment order, ushort4 stores
      int d = n - 128;
      int dh = d >> 5, l31d = d & 31;
#pragma unroll
      for (int mf = 0; mf < 4; ++mf) {
        int mbase = m0 + wr * 64 + mf * 16 + 4 * g;   // 4-aligned
        int kk2 = mbase & 31;
        int kt2 = kk2 >> 4, hh = (kk2 >> 3) & 1;
        size_t off = (size_t)(mbase >> 5) * 2048 +
                     (size_t)((dh * 2 + kt2) * 2 + hh) * 256 + l31d * 8 + (mbase & 7);
        ushort4 pk;
        pk.x = f2bf(acc[mf][nf][0]);
        pk.y = f2bf(acc[mf][nf][1]);
        pk.z = f2bf(acc[mf][nf][2]);
        pk.w = f2bf(acc[mf][nf][3]);
        *(ushort4*)(vo + off) = pk;
      }
    }
  }
}

// ---------------------------------------------------------------------------
// Kernel 3: causal flash attention, LDS-shared KV, (qi x ki) wave grid.
// Grid 1024 x 256 thr. Block = 64 q-rows (bp), wave w = qi*2+ki: q-tile
// rows bp*64+qi*32, KV tiles j == ki (mod 2), j <= diag(qi) = 2bp+qi.
// Round jr: stage tiles 2jr+2,2jr+3 -> vmcnt(4) -> barrier -> each wave
// computes its parity tile -> barrier. Per-CU balance: bp in
// {63-cu, 31-cu, cu, 32+cu}. Sum-merge partner partials via LDS bounce.
// ---------------------------------------------------------------------------
__global__ __launch_bounds__(256, 4) void attn_fwd10(const u16* __restrict__ qg,
                                                     const u16* __restrict__ kg,
                                                     const u16* __restrict__ vg,
                                                     float* __restrict__ out) {
  __shared__ __align__(16) char smem[33792];
  u16* KV = (u16*)smem;            // [2][8192]: K_even|V_even|K_odd|V_odd
  float* MrgF = (float*)smem;      // [4][64][33] after the loop

  int tid = threadIdx.x;
  int lane = tid & 63, w = tid >> 6;
  int l31 = lane & 31, h = lane >> 5;
  int qi = w >> 1, ki = w & 1;

  // mapping: per XCD, m=0: (b0, 63-cu), m=1: (b0, 31-cu), m=2: (b1, cu),
  // m=3: (b1, 32+cu)  => each CU: 260 staged tiles, 516 wave-visits.
  int f = blockIdx.x;
  int xcd = f & 7, i = f >> 3;     // i in [0,128)
  int m = i >> 5, cu = i & 31;
  int b, bp;
  if (m == 0)      { b = 2 * xcd;     bp = 63 - cu; }
  else if (m == 1) { b = 2 * xcd;     bp = 31 - cu; }
  else if (m == 2) { b = 2 * xcd + 1; bp = cu;      }
  else             { b = 2 * xcd + 1; bp = 32 + cu; }

  const int diag = 2 * bp + qi;    // this wave's diagonal KV tile (parity qi)
  const int nr = bp + 1;           // rounds of 2 tiles
  const int q0w = bp * 64 + qi * 32;

  const u16* qb = qg + (size_t)b * NT * HD;
  const u16* kbs = kg + (size_t)b * NT * HD;   // tiled [128][2048]
  const u16* vbs = vg + (size_t)b * NT * HD;
  float* ob = out + (size_t)b * NT * HD;

  // Q fragments (B-operand): lane holds Q[q0w+l31][dt*16 + 8h + jj]
  bf16x8 qf[4];
#pragma unroll
  for (int dt = 0; dt < 4; ++dt)
    qf[dt] = LD8(qb + (size_t)(q0w + l31) * HD + dt * 16 + 8 * h);

  f32x16 oacc0, oacc1;   // O^T[d = dh*32 + (r&3)+8*(r>>2)+4h][q = q0w+l31]
#pragma unroll
  for (int r = 0; r < 16; ++r) { oacc0[r] = 0.f; oacc1[r] = 0.f; }
  float lsum = 0.f;

  auto COMPUTE = [&](const u16* kp0, const u16* vp0, bool maskdiag) {
    bf16x8 kf[4], vf[4];
#pragma unroll
    for (int dt = 0; dt < 4; ++dt)
      kf[dt] = LD8(kp0 + dt * 512 + h * 256 + l31 * 8);
#pragma unroll
    for (int dv = 0; dv < 4; ++dv)   // dv = dh*2+kt
      vf[dv] = LD8(vp0 + dv * 512 + h * 256 + l31 * 8);

    f32x16 sv;
#pragma unroll
    for (int r = 0; r < 16; ++r) sv[r] = 0.f;
    sv = WMFMA(kf[0], qf[0], sv);
    sv = WMFMA(kf[1], qf[1], sv);
    sv = WMFMA(kf[2], qf[2], sv);
    sv = WMFMA(kf[3], qf[3], sv);

    if (maskdiag) {   // diagonal tile: causal mask (q0 cancels)
#pragma unroll
      for (int r = 0; r < 16; ++r) {
        int key = (r & 3) + 8 * (r >> 2) + 4 * h;
        if (key > l31) sv[r] = -1e30f;
      }
    }

    float p[16];
#pragma unroll
    for (int r = 0; r < 16; ++r) p[r] = __builtin_amdgcn_exp2f(sv[r]);
    lsum += (((p[0] + p[1]) + (p[2] + p[3])) + ((p[4] + p[5]) + (p[6] + p[7]))) +
            (((p[8] + p[9]) + (p[10] + p[11])) + ((p[12] + p[13]) + (p[14] + p[15])));
    u32 A0 = cvtpk(p[0], p[1]),   A1 = cvtpk(p[2], p[3]);
    u32 B0 = cvtpk(p[4], p[5]),   B1 = cvtpk(p[6], p[7]);
    u32 C0 = cvtpk(p[8], p[9]),   C1 = cvtpk(p[10], p[11]);
    u32 E0 = cvtpk(p[12], p[13]), E1 = cvtpk(p[14], p[15]);
    u32x2 s0 = lane_swap(A0, B0), s1 = lane_swap(A1, B1);
    u32x2 s2 = lane_swap(C0, E0), s3 = lane_swap(C1, E1);
    union { u32 d[4]; bf16x8 v; } f0u, f1u;   // B-frag: k = 8h+jj
    f0u.d[0] = s0[0]; f0u.d[1] = s1[0]; f0u.d[2] = s0[1]; f0u.d[3] = s1[1];
    f1u.d[0] = s2[0]; f1u.d[1] = s3[0]; f1u.d[2] = s2[1]; f1u.d[3] = s3[1];

    oacc0 = WMFMA(vf[0], f0u.v, oacc0);   // dh=0, kt=0
    oacc1 = WMFMA(vf[2], f0u.v, oacc1);   // dh=1, kt=0
    oacc0 = WMFMA(vf[1], f1u.v, oacc0);   // dh=0, kt=1
    oacc1 = WMFMA(vf[3], f1u.v, oacc1);   // dh=1, kt=1
  };

  // prologue: stage tiles 0,1 into buf 0
  gload16(kbs + tid * 8,        KV + tid * 8);
  gload16(vbs + tid * 8,        KV + 2048 + tid * 8);
  gload16(kbs + 2048 + tid * 8, KV + 4096 + tid * 8);
  gload16(vbs + 2048 + tid * 8, KV + 6144 + tid * 8);

  int cur = 0;
  for (int jr = 0; jr < nr; ++jr) {
    if (jr + 1 < nr) {   // stage next round's 2 tiles into the other buffer
      const u16* gk = kbs + (size_t)(2 * jr + 2) * 2048 + tid * 8;
      const u16* gv = vbs + (size_t)(2 * jr + 2) * 2048 + tid * 8;
      u16* lb = KV + (cur ^ 1) * 8192;
      gload16(gk,        lb + tid * 8);
      gload16(gv,        lb + 2048 + tid * 8);
      gload16(gk + 2048, lb + 4096 + tid * 8);
      gload16(gv + 2048, lb + 6144 + tid * 8);
      asm volatile("s_waitcnt vmcnt(4)" ::: "memory");   // this round landed
    } else {
      asm volatile("s_waitcnt vmcnt(0)" ::: "memory");
    }
    __builtin_amdgcn_sched_barrier(0);
    asm volatile("s_barrier" ::: "memory");

    const u16* kv0 = KV + cur * 8192;
    int jmine = 2 * jr + ki;       // this wave's parity tile in the round
    if (jmine <= diag)
      COMPUTE(kv0 + ki * 4096, kv0 + ki * 4096 + 2048, jmine == diag);

    asm volatile("s_barrier" ::: "memory");
    cur ^= 1;
  }

  // publish partials (raw O + lsum); partner waves (qi,0)+(qi,1) sum-merge
  lsum += __shfl_xor(lsum, 32);
  {
    float* mg = MrgF + ((size_t)w * 64 + lane) * 33;
#pragma unroll
    for (int r = 0; r < 16; ++r) { mg[r] = oacc0[r]; mg[16 + r] = oacc1[r]; }
    mg[32] = lsum;
  }
  __syncthreads();
  // wave w writes q-tile qi's rows, d-columns [ki*32, ki*32+32)
#pragma unroll
  for (int s = 0; s < 4; ++s) {
    int ql = (lane >> 2) + 16 * (s & 1);          // [0,32)
    int dq = ki * 8 + (lane & 3) + 4 * (s >> 1);  // [ki*8, ki*8+8)
    const float* m0p = MrgF + ((size_t)(qi * 2) * 64) * 33;
    const float* m1p = MrgF + ((size_t)(qi * 2 + 1) * 64) * 33;
    float ls = m0p[(size_t)ql * 33 + 32] + m1p[(size_t)ql * 33 + 32];
    float inv = 1.0f / ls;
    f32x4 o4;
#pragma unroll
    for (int dd = 0; dd < 4; ++dd) {
      int d = dq * 4 + dd;
      int dh = d >> 5, rem = d & 31;
      int srch = (rem >> 2) & 1;
      int reg = dh * 16 + (rem & 3) + ((rem >> 3) << 2);
      size_t ro = (size_t)(ql + 32 * srch) * 33 + reg;
      o4[dd] = (m0p[ro] + m1p[ro]) * inv;
    }
    *(f32x4*)(ob + (size_t)(q0w + ql) * HD + dq * 4) = o4;
  }
}

// ---------------------------------------------------------------------------
extern "C" void kernel_launch(void* const* d_in, const int* in_sizes, int n_in,
                              void* d_out, int out_size, void* d_ws, size_t ws_size,
                              hipStream_t stream) {
  const float* x  = (const float*)d_in[0];
  const float* Wq = (const float*)d_in[1];
  const float* Wk = (const float*)d_in[2];
  const float* Wv = (const float*)d_in[3];
  float* out = (float*)d_out;

  // ws layout: Wt bf16 [192][512] | q [B*T][64] | k tiled | v tiled
  u16* Wt  = (u16*)d_ws;
  u16* qws = (u16*)((char*)d_ws + 192 * 512 * 2);
  u16* kws = qws + (size_t)NB * NT * HD;
  u16* vws = kws + (size_t)NB * NT * HD;

  prep_wt<<<32, 256, 0, stream>>>(Wq, Wk, Wv, Wt);
  proj_qkv<<<(NB * NT) / 128, 512, 0, stream>>>(x, Wt, qws, kws, vws);
  attn_fwd10<<<1024, 256, 0, stream>>>(qws, kws, vws, out);
}

// Round 11
// 91.391 us; speedup vs baseline: 1.8055x; 1.0587x over previous
//
#include <hip/hip_runtime.h>
#include <hip/hip_bf16.h>
#include <math.h>

// Single-head causal attention with fused QKV projection.
// B=16, T=4096, D_MODEL=512, HEAD_DIM=64. fp32 in/out, bf16 MFMA internally.
//
// R11: attn rounds lengthened to 4 KV tiles per barrier pair (wave computes
// 2 tiles of its parity sequentially) -> ~65 rounds/CU instead of 130; LDS
// 2x32KB double buffer (2 blocks/CU), wave-owned staging with clamped loads
// so vmcnt(8) stays exact; setprio(1) around compute. proj: distance-2 x
// prefetch + scalar __float2bfloat16 casts (compiler emits cvt_pk).
// In-register P core unchanged (swapped 32x32 QK^T, cvt_pk+permlane32_swap,
// max-free softmax, scale pre-folded into Q).

#define NB 16
#define NT 4096
#define DMODEL 512
#define HD 64
#define CEXP 0.18033688011112042f   // log2(e)/8

typedef unsigned short u16;
typedef unsigned int u32;
typedef __attribute__((ext_vector_type(2))) unsigned int u32x2;
typedef __attribute__((ext_vector_type(8))) short bf16x8;
typedef __attribute__((ext_vector_type(4))) float f32x4;
typedef __attribute__((ext_vector_type(16))) float f32x16;

__device__ __forceinline__ u16 bfu(float x) {
  __hip_bfloat16 h = __float2bfloat16(x);
  return *(u16*)&h;
}

__device__ __forceinline__ u32 cvtpk(float lo, float hi) {
  u32 r;
  asm("v_cvt_pk_bf16_f32 %0, %1, %2" : "=v"(r) : "v"(lo), "v"(hi));
  return r;
}

// v_permlane32_swap_b32: a'[i<32]=a[i], a'[i>=32]=b[i-32]; b'[i<32]=a[i+32].
__device__ __forceinline__ u32x2 lane_swap(u32 a, u32 b) {
  asm("v_permlane32_swap_b32 %0, %1" : "+v"(a), "+v"(b));
  u32x2 r; r[0] = a; r[1] = b; return r;
}

__device__ __forceinline__ void gload16(const void* g, void* l) {
  __builtin_amdgcn_global_load_lds(
      (const __attribute__((address_space(1))) void*)g,
      (__attribute__((address_space(3))) void*)l, 16, 0, 0);
}

#define MFMA32(a, b, c) __builtin_amdgcn_mfma_f32_16x16x32_bf16(a, b, c, 0, 0, 0)
#define WMFMA(a, b, c)  __builtin_amdgcn_mfma_f32_32x32x16_bf16(a, b, c, 0, 0, 0)
#define LD8(p) (*(const bf16x8*)(p))

// ---------------------------------------------------------------------------
// Kernel 1: Wt[n][k] = W_{n/64}[k][n%64] as bf16, n in [0,192), k in [0,512).
// ---------------------------------------------------------------------------
__global__ void prep_wt(const float* __restrict__ Wq, const float* __restrict__ Wk,
                        const float* __restrict__ Wv, u16* __restrict__ Wt) {
  int k0 = blockIdx.x * 16;
  int t = threadIdx.x;
#pragma unroll
  for (int i = 0; i < 12; ++i) {
    int idx = t + i * 256;      // [0, 3072)
    int n = idx % 192;
    int kk = idx / 192;         // [0, 16)
    const float* W = (n < 64) ? Wq : (n < 128) ? Wk : Wv;
    float w = W[(size_t)(k0 + kk) * 64 + (n & 63)];
    Wt[(size_t)n * 512 + k0 + kk] = bfu(w);
  }
}

// ---------------------------------------------------------------------------
// Kernel 2: q = (x@Wq)*CEXP row-major bf16 [B*T][64];
//   k tiled fragment-order: kt[b*128+tile][dt][h][l31][8] = K[key][d]
//   v tiled fragment-order: vt[b*128+tile][dh][kt][h][l31][8] = V[key][d]
// 512 threads (8 waves, 2x4), BM=128, BN=192, BK=32, distance-2 x prefetch.
// ---------------------------------------------------------------------------
__global__ __launch_bounds__(512) void proj_qkv(const float* __restrict__ x,
                                                const u16* __restrict__ Wt,
                                                u16* __restrict__ qo,
                                                u16* __restrict__ ko,
                                                u16* __restrict__ vo) {
  __shared__ u16 As[128][48];   // 32 k + 16 pad
  int t = threadIdx.x;
  int m0 = blockIdx.x * 128;
  int lane = t & 63, wid = t >> 6;
  int wr = wid >> 2, wc = wid & 3;
  int g = lane >> 4, li = lane & 15;
  f32x4 acc[4][3];
#pragma unroll
  for (int i = 0; i < 4; ++i)
#pragma unroll
    for (int j = 0; j < 3; ++j) acc[i][j] = (f32x4){0.f, 0.f, 0.f, 0.f};

  int row = t >> 2, quad = t & 3;
  const float* srcb = x + (size_t)(m0 + row) * DMODEL + quad * 8;

  float4 pa0[2], pa1[2];   // distance-2 prefetch slots (static idx via unroll)
  pa0[0] = *(const float4*)(srcb);       pa1[0] = *(const float4*)(srcb + 4);
  pa0[1] = *(const float4*)(srcb + 32);  pa1[1] = *(const float4*)(srcb + 36);

#pragma unroll
  for (int s = 0; s < 16; ++s) {
    float4 c0 = pa0[s & 1], c1 = pa1[s & 1];
    if (s + 2 < 16) {
      pa0[s & 1] = *(const float4*)(srcb + (s + 2) * 32);
      pa1[s & 1] = *(const float4*)(srcb + (s + 2) * 32 + 4);
    }
    __syncthreads();   // WAR: previous step's LDS reads complete
    union { u16 u[8]; bf16x8 v; } tmp;
    tmp.u[0] = bfu(c0.x); tmp.u[1] = bfu(c0.y);
    tmp.u[2] = bfu(c0.z); tmp.u[3] = bfu(c0.w);
    tmp.u[4] = bfu(c1.x); tmp.u[5] = bfu(c1.y);
    tmp.u[6] = bfu(c1.z); tmp.u[7] = bfu(c1.w);
    *(bf16x8*)&As[row][quad * 8] = tmp.v;
    __syncthreads();

    int k0 = s * 32;
    bf16x8 a[4], bb[3];
#pragma unroll
    for (int mf = 0; mf < 4; ++mf)
      a[mf] = *(const bf16x8*)&As[wr * 64 + mf * 16 + li][g * 8];
#pragma unroll
    for (int nf = 0; nf < 3; ++nf)
      bb[nf] = *(const bf16x8*)(Wt + (size_t)(wc * 48 + nf * 16 + li) * 512 + k0 + g * 8);
#pragma unroll
    for (int mf = 0; mf < 4; ++mf)
#pragma unroll
      for (int nf = 0; nf < 3; ++nf)
        acc[mf][nf] = MFMA32(a[mf], bb[nf], acc[mf][nf]);
  }

  // D layout: col = lane&15, row = 4*(lane>>4)+r
#pragma unroll
  for (int nf = 0; nf < 3; ++nf) {
    int n = wc * 48 + nf * 16 + li;
    if (n < 64) {            // Q: row-major, scale folded (in f32)
      int col = n;
#pragma unroll
      for (int mf = 0; mf < 4; ++mf)
#pragma unroll
        for (int r = 0; r < 4; ++r) {
          int m = m0 + wr * 64 + mf * 16 + 4 * g + r;
          qo[(size_t)m * HD + col] = bfu(acc[mf][nf][r] * CEXP);
        }
    } else if (n < 128) {    // K: tiled fragment order
      int col = n & 63;
      int dt = col >> 4, hh = (col >> 3) & 1, jj = col & 7;
      size_t fo = (size_t)(dt * 2 + hh) * 256 + jj;
#pragma unroll
      for (int mf = 0; mf < 4; ++mf)
#pragma unroll
        for (int r = 0; r < 4; ++r) {
          int m = m0 + wr * 64 + mf * 16 + 4 * g + r;
          ko[(size_t)(m >> 5) * 2048 + fo + (m & 31) * 8] = bfu(acc[mf][nf][r]);
        }
    } else {                 // V: tiled fragment order, ushort4 stores
      int d = n - 128;
      int dh = d >> 5, l31d = d & 31;
#pragma unroll
      for (int mf = 0; mf < 4; ++mf) {
        int mbase = m0 + wr * 64 + mf * 16 + 4 * g;   // 4-aligned
        int kk2 = mbase & 31;
        int kt2 = kk2 >> 4, hh = (kk2 >> 3) & 1;
        size_t off = (size_t)(mbase >> 5) * 2048 +
                     (size_t)((dh * 2 + kt2) * 2 + hh) * 256 + l31d * 8 + (mbase & 7);
        ushort4 pk;
        pk.x = bfu(acc[mf][nf][0]);
        pk.y = bfu(acc[mf][nf][1]);
        pk.z = bfu(acc[mf][nf][2]);
        pk.w = bfu(acc[mf][nf][3]);
        *(ushort4*)(vo + off) = pk;
      }
    }
  }
}

// ---------------------------------------------------------------------------
// Kernel 3: causal flash attention, LDS-shared KV, 4 tiles/barrier-round.
// Grid 1024 x 256 thr. Block = 64 q-rows (bp), wave w = qi*2+ki: q-tile
// rows bp*64+qi*32, KV tiles j == ki (mod 2), j <= diag = 2bp+qi; each wave
// computes 2 tiles per round. Wave w stages K/V of local tile w (clamped, so
// every wave issues exactly 8 gload16 per staging round -> vmcnt(8) exact).
// LDS: 2 x 32KB double buffer, output bounce unioned. LPT: bp descending.
// ---------------------------------------------------------------------------
__global__ __launch_bounds__(256, 2) void attn_fwd11(const u16* __restrict__ qg,
                                                     const u16* __restrict__ kg,
                                                     const u16* __restrict__ vg,
                                                     float* __restrict__ out) {
  __shared__ __align__(16) char smem[65536];
  u16* KV = (u16*)smem;            // [2][16384]: (K0|V0|K1|V1|K2|V2|K3|V3)
  float* MrgF = (float*)smem;      // [4][64][33] after the loop

  int tid = threadIdx.x;
  int lane = tid & 63, w = tid >> 6;
  int l31 = lane & 31, h = lane >> 5;
  int qi = w >> 1, ki = w & 1;

  // LPT + XCD: xcd = f&7 owns batches {2xcd, 2xcd+1}; bp descending.
  int f = blockIdx.x;
  int xcd = f & 7, i = f >> 3;     // i in [0,128)
  int b = 2 * xcd + (i & 1);
  int bp = 63 - (i >> 1);

  const int limb = 2 * bp + 1;     // last KV tile needed by the block
  const int diagw = 2 * bp + qi;   // this wave's diagonal tile (parity qi)
  const int nr = (bp + 2) >> 1;    // rounds of 4 tiles
  const int q0w = bp * 64 + qi * 32;

  const u16* qb = qg + (size_t)b * NT * HD;
  const u16* kbs = kg + (size_t)b * NT * HD;   // tiled [128][2048]
  const u16* vbs = vg + (size_t)b * NT * HD;
  float* ob = out + (size_t)b * NT * HD;

  // Q fragments (B-operand): lane holds Q[q0w+l31][dt*16 + 8h + jj]
  bf16x8 qf[4];
#pragma unroll
  for (int dt = 0; dt < 4; ++dt)
    qf[dt] = LD8(qb + (size_t)(q0w + l31) * HD + dt * 16 + 8 * h);

  f32x16 oacc0, oacc1;   // O^T[d = dh*32 + (r&3)+8*(r>>2)+4h][q = q0w+l31]
#pragma unroll
  for (int r = 0; r < 16; ++r) { oacc0[r] = 0.f; oacc1[r] = 0.f; }
  float lsum = 0.f;

  auto STAGE = [&](u16* lb, int tg) {   // stage K_tg,V_tg into wave slot w
    const u16* gk = kbs + (size_t)tg * 2048 + lane * 8;
    const u16* gv = vbs + (size_t)tg * 2048 + lane * 8;
    u16* dk = lb + w * 4096 + lane * 8;
#pragma unroll
    for (int ii = 0; ii < 4; ++ii) {
      gload16(gk + ii * 512, dk + ii * 512);
      gload16(gv + ii * 512, dk + 2048 + ii * 512);
    }
  };

  auto COMPUTE = [&](const u16* kp0, const u16* vp0, bool maskdiag) {
    bf16x8 kf[4], vf[4];
#pragma unroll
    for (int dt = 0; dt < 4; ++dt)
      kf[dt] = LD8(kp0 + dt * 512 + h * 256 + l31 * 8);
#pragma unroll
    for (int dv = 0; dv < 4; ++dv)   // dv = dh*2+kt
      vf[dv] = LD8(vp0 + dv * 512 + h * 256 + l31 * 8);

    f32x16 sv;
#pragma unroll
    for (int r = 0; r < 16; ++r) sv[r] = 0.f;
    sv = WMFMA(kf[0], qf[0], sv);
    sv = WMFMA(kf[1], qf[1], sv);
    sv = WMFMA(kf[2], qf[2], sv);
    sv = WMFMA(kf[3], qf[3], sv);

    if (maskdiag) {   // diagonal tile: causal mask (q0 cancels)
#pragma unroll
      for (int r = 0; r < 16; ++r) {
        int key = (r & 3) + 8 * (r >> 2) + 4 * h;
        if (key > l31) sv[r] = -1e30f;
      }
    }

    float p[16];
#pragma unroll
    for (int r = 0; r < 16; ++r) p[r] = __builtin_amdgcn_exp2f(sv[r]);
    lsum += (((p[0] + p[1]) + (p[2] + p[3])) + ((p[4] + p[5]) + (p[6] + p[7]))) +
            (((p[8] + p[9]) + (p[10] + p[11])) + ((p[12] + p[13]) + (p[14] + p[15])));
    u32 A0 = cvtpk(p[0], p[1]),   A1 = cvtpk(p[2], p[3]);
    u32 B0 = cvtpk(p[4], p[5]),   B1 = cvtpk(p[6], p[7]);
    u32 C0 = cvtpk(p[8], p[9]),   C1 = cvtpk(p[10], p[11]);
    u32 E0 = cvtpk(p[12], p[13]), E1 = cvtpk(p[14], p[15]);
    u32x2 s0 = lane_swap(A0, B0), s1 = lane_swap(A1, B1);
    u32x2 s2 = lane_swap(C0, E0), s3 = lane_swap(C1, E1);
    union { u32 d[4]; bf16x8 v; } f0u, f1u;   // B-frag: k = 8h+jj
    f0u.d[0] = s0[0]; f0u.d[1] = s1[0]; f0u.d[2] = s0[1]; f0u.d[3] = s1[1];
    f1u.d[0] = s2[0]; f1u.d[1] = s3[0]; f1u.d[2] = s2[1]; f1u.d[3] = s3[1];

    oacc0 = WMFMA(vf[0], f0u.v, oacc0);   // dh=0, kt=0
    oacc1 = WMFMA(vf[2], f0u.v, oacc1);   // dh=1, kt=0
    oacc0 = WMFMA(vf[1], f1u.v, oacc0);   // dh=0, kt=1
    oacc1 = WMFMA(vf[3], f1u.v, oacc1);   // dh=1, kt=1
  };

  // prologue: stage round 0's 4 tiles (clamped) into buf 0
  STAGE(KV, min(w, limb));

  int cur = 0;
  for (int jr = 0; jr < nr; ++jr) {
    if (jr + 1 < nr) {   // stage next round's tiles (clamped -> always 8 loads)
      STAGE(KV + (cur ^ 1) * 16384, min(4 * (jr + 1) + w, limb));
      asm volatile("s_waitcnt vmcnt(8)" ::: "memory");   // this round landed
    } else {
      asm volatile("s_waitcnt vmcnt(0)" ::: "memory");
    }
    __builtin_amdgcn_sched_barrier(0);
    asm volatile("s_barrier" ::: "memory");

    const u16* kv0 = KV + cur * 16384;
    int j1 = 4 * jr + ki, j2 = 4 * jr + 2 + ki;   // local tiles ki, 2+ki
    __builtin_amdgcn_s_setprio(1);
    if (j1 <= diagw)
      COMPUTE(kv0 + ki * 4096, kv0 + ki * 4096 + 2048, j1 == diagw);
    if (j2 <= diagw)
      COMPUTE(kv0 + (2 + ki) * 4096, kv0 + (2 + ki) * 4096 + 2048, j2 == diagw);
    __builtin_amdgcn_s_setprio(0);

    asm volatile("s_barrier" ::: "memory");
    cur ^= 1;
  }

  // publish partials (raw O + lsum); partner waves (qi,0)+(qi,1) sum-merge
  lsum += __shfl_xor(lsum, 32);
  {
    float* mg = MrgF + ((size_t)w * 64 + lane) * 33;
#pragma unroll
    for (int r = 0; r < 16; ++r) { mg[r] = oacc0[r]; mg[16 + r] = oacc1[r]; }
    mg[32] = lsum;
  }
  __syncthreads();
  // wave w writes q-tile qi's rows, d-columns [ki*32, ki*32+32)
#pragma unroll
  for (int s = 0; s < 4; ++s) {
    int ql = (lane >> 2) + 16 * (s & 1);          // [0,32)
    int dq = ki * 8 + (lane & 3) + 4 * (s >> 1);  // [ki*8, ki*8+8)
    const float* m0p = MrgF + ((size_t)(qi * 2) * 64) * 33;
    const float* m1p = MrgF + ((size_t)(qi * 2 + 1) * 64) * 33;
    float ls = m0p[(size_t)ql * 33 + 32] + m1p[(size_t)ql * 33 + 32];
    float inv = 1.0f / ls;
    f32x4 o4;
#pragma unroll
    for (int dd = 0; dd < 4; ++dd) {
      int d = dq * 4 + dd;
      int dh = d >> 5, rem = d & 31;
      int srch = (rem >> 2) & 1;
      int reg = dh * 16 + (rem & 3) + ((rem >> 3) << 2);
      size_t ro = (size_t)(ql + 32 * srch) * 33 + reg;
      o4[dd] = (m0p[ro] + m1p[ro]) * inv;
    }
    *(f32x4*)(ob + (size_t)(q0w + ql) * HD + dq * 4) = o4;
  }
}

// ---------------------------------------------------------------------------
extern "C" void kernel_launch(void* const* d_in, const int* in_sizes, int n_in,
                              void* d_out, int out_size, void* d_ws, size_t ws_size,
                              hipStream_t stream) {
  const float* x  = (const float*)d_in[0];
  const float* Wq = (const float*)d_in[1];
  const float* Wk = (const float*)d_in[2];
  const float* Wv = (const float*)d_in[3];
  float* out = (float*)d_out;

  // ws layout: Wt bf16 [192][512] | q [B*T][64] | k tiled | v tiled
  u16* Wt  = (u16*)d_ws;
  u16* qws = (u16*)((char*)d_ws + 192 * 512 * 2);
  u16* kws = qws + (size_t)NB * NT * HD;
  u16* vws = kws + (size_t)NB * NT * HD;

  prep_wt<<<32, 256, 0, stream>>>(Wq, Wk, Wv, Wt);
  proj_qkv<<<(NB * NT) / 128, 512, 0, stream>>>(x, Wt, qws, kws, vws);
  attn_fwd11<<<1024, 256, 0, stream>>>(qws, kws, vws, out);
}